// Round 1
// baseline (1332.773 us; speedup 1.0000x reference)
//
#include <hip/hip_runtime.h>
#include <math.h>

// ContrastiveLoss: B samples x 4 embeddings x 1024 fp32.
// One wave (64 lanes) per sample: coalesced float4 loads, 10-entry Gram
// accumulation in registers, shfl reduction, lane-0 scalar epilogue.
// Memory-bound: 1 GiB read -> ~170us floor at 6.3 TB/s.

#define INV_TEMP 14.285714285714286f  // 1/0.07
#define NORM_EPS 1e-12f

__global__ __launch_bounds__(256) void cl_main(const float* __restrict__ emb,
                                               const int* __restrict__ labels,
                                               double* __restrict__ acc_ws,
                                               int B)
{
    const int lane  = threadIdx.x & 63;
    const int wid   = threadIdx.x >> 6;
    const int gwave = blockIdx.x * 4 + wid;
    const int nwave = gridDim.x * 4;

    double local_total = 0.0;
    double local_count = 0.0;

    for (int s = gwave; s < B; s += nwave) {
        const float4* base = (const float4*)(emb + (size_t)s * 4096);

        float a00 = 0.f, a01 = 0.f, a02 = 0.f, a03 = 0.f;
        float a11 = 0.f, a12 = 0.f, a13 = 0.f;
        float a22 = 0.f, a23 = 0.f, a33 = 0.f;

#pragma unroll
        for (int k = 0; k < 4; ++k) {
            const int idx = k * 64 + lane;          // 256 float4 per vector
            float4 v0 = base[idx];
            float4 v1 = base[256 + idx];
            float4 v2 = base[512 + idx];
            float4 v3 = base[768 + idx];

            a00 += v0.x*v0.x + v0.y*v0.y + v0.z*v0.z + v0.w*v0.w;
            a01 += v0.x*v1.x + v0.y*v1.y + v0.z*v1.z + v0.w*v1.w;
            a02 += v0.x*v2.x + v0.y*v2.y + v0.z*v2.z + v0.w*v2.w;
            a03 += v0.x*v3.x + v0.y*v3.y + v0.z*v3.z + v0.w*v3.w;
            a11 += v1.x*v1.x + v1.y*v1.y + v1.z*v1.z + v1.w*v1.w;
            a12 += v1.x*v2.x + v1.y*v2.y + v1.z*v2.z + v1.w*v2.w;
            a13 += v1.x*v3.x + v1.y*v3.y + v1.z*v3.z + v1.w*v3.w;
            a22 += v2.x*v2.x + v2.y*v2.y + v2.z*v2.z + v2.w*v2.w;
            a23 += v2.x*v3.x + v2.y*v3.y + v2.z*v3.z + v2.w*v3.w;
            a33 += v3.x*v3.x + v3.y*v3.y + v3.z*v3.z + v3.w*v3.w;
        }

        // wave-wide sum (width 64); result valid on lane 0
#define RED64(x) { x += __shfl_down(x, 32, 64); x += __shfl_down(x, 16, 64); \
                   x += __shfl_down(x,  8, 64); x += __shfl_down(x,  4, 64); \
                   x += __shfl_down(x,  2, 64); x += __shfl_down(x,  1, 64); }
        RED64(a00) RED64(a01) RED64(a02) RED64(a03)
        RED64(a11) RED64(a12) RED64(a13)
        RED64(a22) RED64(a23) RED64(a33)
#undef RED64

        if (lane == 0) {
            const int* lb = labels + (size_t)s * 4;
            const int L[4] = { lb[0], lb[1], lb[2], lb[3] };
            const int P = L[0] + L[1] + L[2] + L[3];
            const int N = 4 - P;

            if (P > 0 && N > 0) {
                float g[4][4];
                g[0][0] = a00; g[0][1] = a01; g[0][2] = a02; g[0][3] = a03;
                g[1][0] = a01; g[1][1] = a11; g[1][2] = a12; g[1][3] = a13;
                g[2][0] = a02; g[2][1] = a12; g[2][2] = a22; g[2][3] = a23;
                g[3][0] = a03; g[3][1] = a13; g[3][2] = a23; g[3][3] = a33;

                float inv[4];
#pragma unroll
                for (int i = 0; i < 4; ++i)
                    inv[i] = 1.0f / fmaxf(sqrtf(g[i][i]), NORM_EPS);

                float e[4][4];
#pragma unroll
                for (int i = 0; i < 4; ++i)
#pragma unroll
                    for (int j = 0; j < 4; ++j)
                        e[i][j] = __expf(g[i][j] * inv[i] * inv[j] * INV_TEMP);

                float contrib = 0.0f;
                // negative term: per positive row, log1p(sum over negative cols)
#pragma unroll
                for (int i = 0; i < 4; ++i) {
                    if (L[i] == 1) {
                        float ns = 0.0f;
#pragma unroll
                        for (int j = 0; j < 4; ++j)
                            if (L[j] == 0) ns += e[i][j];
                        contrib += log1pf(ns);
                    }
                }
                float cnt = (float)P;
                // positive term: -log(mean over full PxP block) when P > 1
                if (P > 1) {
                    float ps = 0.0f;
#pragma unroll
                    for (int i = 0; i < 4; ++i)
                        if (L[i] == 1)
#pragma unroll
                            for (int j = 0; j < 4; ++j)
                                if (L[j] == 1) ps += e[i][j];
                    contrib -= logf(ps / (float)(P * P));
                    cnt += 1.0f;
                }
                local_total += (double)contrib;
                local_count += (double)cnt;
            }
        }
    }

    __shared__ double st[4], sc[4];
    if (lane == 0) { st[wid] = local_total; sc[wid] = local_count; }
    __syncthreads();
    if (threadIdx.x == 0) {
        double t = st[0] + st[1] + st[2] + st[3];
        double c = sc[0] + sc[1] + sc[2] + sc[3];
        atomicAdd(acc_ws, t);
        atomicAdd(acc_ws + 1, c);
    }
}

__global__ void cl_finalize(const double* __restrict__ acc_ws,
                            float* __restrict__ out)
{
    out[0] = (float)(acc_ws[0] / fmax(acc_ws[1], 1.0));
}

extern "C" void kernel_launch(void* const* d_in, const int* in_sizes, int n_in,
                              void* d_out, int out_size, void* d_ws, size_t ws_size,
                              hipStream_t stream) {
    const float* emb    = (const float*)d_in[0];
    const int*   labels = (const int*)d_in[1];
    float*  out = (float*)d_out;
    double* ws  = (double*)d_ws;

    const int B = in_sizes[0] / 4096;   // 4 vectors x 1024 floats per sample

    hipMemsetAsync(d_ws, 0, 2 * sizeof(double), stream);
    cl_main<<<2048, 256, 0, stream>>>(emb, labels, ws, B);
    cl_finalize<<<1, 1, 0, stream>>>(ws, out);
}